// Round 1
// baseline (10814.651 us; speedup 1.0000x reference)
//
#include <hip/hip_runtime.h>
#include <hip/hip_bf16.h>

#define Bsz 256
#define Tlen 512
#define Dd 512
#define Hh 1024
#define G4 4096
#define NOUT 8

typedef short s16x8 __attribute__((ext_vector_type(8)));
typedef float f32x4 __attribute__((ext_vector_type(4)));

__device__ __forceinline__ ushort f2bf(float f) {
    union { float f; uint u; } v; v.f = f;
    uint u = v.u;
    uint r = u + 0x7FFFu + ((u >> 16) & 1u);   // round-to-nearest-even
    return (ushort)(r >> 16);
}
__device__ __forceinline__ float bf2f(ushort u) {
    union { uint u; float f; } v; v.u = ((uint)u) << 16; return v.f;
}
__device__ __forceinline__ float sigf(float x) { return 1.f / (1.f + __expf(-x)); }
__device__ __forceinline__ float tanhfast(float x) {
    float ax = fabsf(x);
    float e = __expf(-2.f * ax);
    float t = (1.f - e) / (1.f + e);
    return copysignf(t, x);
}

// ---------------- init: zero h0 (bf16) and c (fp32) ----------------
__global__ void init_kernel(uint4* __restrict__ h0, uint4* __restrict__ c) {
    int i = blockIdx.x * 256 + threadIdx.x;       // 65536 threads
    uint4 z = make_uint4(0u, 0u, 0u, 0u);
    c[i] = z;                                     // 65536 uint4 = 1 MB
    if (i < 32768) h0[i] = z;                     // 32768 uint4 = 512 KB
}

// ---------------- fp32 -> bf16 convert ----------------
__global__ void cvt_kernel(const float4* __restrict__ src, ushort4* __restrict__ dst, int n4) {
    int i = blockIdx.x * 256 + threadIdx.x;
    if (i >= n4) return;
    float4 v = src[i];
    ushort4 w;
    w.x = f2bf(v.x); w.y = f2bf(v.y); w.z = f2bf(v.z); w.w = f2bf(v.w);
    dst[i] = w;
}

// ---------------- one LSTM time step ----------------
// grid 256 blocks (4 batch-tiles x 64 col-tiles), 256 threads (4 waves).
// Block computes gates[64 batch][64 gate-cols] where the 64 gate cols are
// {g*1024 + j0 + cc : g in 0..3, cc in 0..15}, then updates c,h for its
// 64x16 (batch x h-col) patch.
__launch_bounds__(256)
__global__ void lstm_step(const float* __restrict__ x,
                          const ushort* __restrict__ Wih,   // bf16 [4096][512]
                          const ushort* __restrict__ Whh,   // bf16 [4096][1024]
                          const float* __restrict__ b_ih,
                          const float* __restrict__ b_hh,
                          const ushort* __restrict__ h_prev, // bf16 [256][1024]
                          ushort* __restrict__ h_next,       // bf16 [256][1024]
                          float* __restrict__ c,             // fp32 [256][1024]
                          int t) {
    __shared__ ushort At[64 * 64];
    __shared__ ushort Bt[64 * 64];
    __shared__ float gates[64 * 72];

    const int tid  = threadIdx.x;
    const int lane = tid & 63;
    const int wid  = tid >> 6;     // 0..3
    const int wr   = wid >> 1;     // wave row half
    const int wc   = wid & 1;      // wave col half
    const int bt   = blockIdx.x >> 6;   // 0..3
    const int jt   = blockIdx.x & 63;   // 0..63
    const int b0   = bt * 64;
    const int j0   = jt * 16;

    f32x4 acc[2][2] = {};

    auto mfma_tile = [&]() {
        #pragma unroll
        for (int ks = 0; ks < 2; ++ks) {
            const int koff = ks * 32 + ((lane >> 4) << 3);
            const int kc   = koff >> 3;
            s16x8 a[2], bfr[2];
            #pragma unroll
            for (int m = 0; m < 2; ++m) {
                int row = wr * 32 + m * 16 + (lane & 15);
                a[m] = *(const s16x8*)&At[row * 64 + ((kc ^ (row & 7)) << 3)];
            }
            #pragma unroll
            for (int n = 0; n < 2; ++n) {
                int col = wc * 32 + n * 16 + (lane & 15);
                bfr[n] = *(const s16x8*)&Bt[col * 64 + ((kc ^ (col & 7)) << 3)];
            }
            #pragma unroll
            for (int m = 0; m < 2; ++m)
                #pragma unroll
                for (int n = 0; n < 2; ++n)
                    acc[m][n] = __builtin_amdgcn_mfma_f32_16x16x32_bf16(a[m], bfr[n], acc[m][n], 0, 0, 0);
        }
    };

    // ---- phase X: K over D (x fp32 -> bf16, Wih bf16) ----
    for (int kb = 0; kb < Dd; kb += 64) {
        __syncthreads();
        #pragma unroll
        for (int it = 0; it < 4; ++it) {           // A: 64 rows x 64 k from x
            int idx = tid + it * 256;              // 0..1023
            int row = idx >> 4;
            int k   = (idx & 15) * 4;
            const float4 v = *(const float4*)&x[(size_t)(b0 + row) * (Tlen * Dd) + (size_t)t * Dd + kb + k];
            ushort4 w;
            w.x = f2bf(v.x); w.y = f2bf(v.y); w.z = f2bf(v.z); w.w = f2bf(v.w);
            int dst = row * 64 + (((k >> 3) ^ (row & 7)) << 3) + (k & 7);
            *(ushort4*)&At[dst] = w;
        }
        #pragma unroll
        for (int it = 0; it < 2; ++it) {           // B: 64 cols x 64 k from Wih
            int idx = tid + it * 256;              // 0..511
            int col = idx >> 3;
            int kc  = idx & 7;
            int grow = ((col >> 4) << 10) + j0 + (col & 15);
            uint4 v = *(const uint4*)&Wih[(size_t)grow * Dd + kb + kc * 8];
            *(uint4*)&Bt[col * 64 + ((kc ^ (col & 7)) << 3)] = v;
        }
        __syncthreads();
        mfma_tile();
    }

    // ---- phase H: K over H (h_prev bf16, Whh bf16) ----
    for (int kb = 0; kb < Hh; kb += 64) {
        __syncthreads();
        #pragma unroll
        for (int it = 0; it < 2; ++it) {           // A: 64 rows x 64 k from h_prev
            int idx = tid + it * 256;
            int row = idx >> 3;
            int kc  = idx & 7;
            uint4 v = *(const uint4*)&h_prev[(size_t)(b0 + row) * Hh + kb + kc * 8];
            *(uint4*)&At[row * 64 + ((kc ^ (row & 7)) << 3)] = v;
        }
        #pragma unroll
        for (int it = 0; it < 2; ++it) {           // B: 64 cols x 64 k from Whh
            int idx = tid + it * 256;
            int col = idx >> 3;
            int kc  = idx & 7;
            int grow = ((col >> 4) << 10) + j0 + (col & 15);
            uint4 v = *(const uint4*)&Whh[(size_t)grow * Hh + kb + kc * 8];
            *(uint4*)&Bt[col * 64 + ((kc ^ (col & 7)) << 3)] = v;
        }
        __syncthreads();
        mfma_tile();
    }

    // ---- epilogue: gates -> LDS ----
    #pragma unroll
    for (int m = 0; m < 2; ++m)
        #pragma unroll
        for (int n = 0; n < 2; ++n)
            #pragma unroll
            for (int j = 0; j < 4; ++j) {
                int row = wr * 32 + m * 16 + ((lane >> 4) << 2) + j;
                int col = wc * 32 + n * 16 + (lane & 15);
                gates[row * 72 + col] = acc[m][n][j];
            }
    __syncthreads();

    // ---- activations + cell update: 64 rows x 16 h-cols ----
    #pragma unroll
    for (int it = 0; it < 4; ++it) {
        int idx = tid + it * 256;                  // 0..1023
        int row = idx >> 4;
        int cc  = idx & 15;
        int gcol = j0 + cc;
        float gi = gates[row * 72 + cc]      + b_ih[gcol]          + b_hh[gcol];
        float gf = gates[row * 72 + 16 + cc] + b_ih[Hh + gcol]     + b_hh[Hh + gcol];
        float gg = gates[row * 72 + 32 + cc] + b_ih[2 * Hh + gcol] + b_hh[2 * Hh + gcol];
        float go = gates[row * 72 + 48 + cc] + b_ih[3 * Hh + gcol] + b_hh[3 * Hh + gcol];
        float i_ = sigf(gi);
        float f_ = sigf(gf);
        float g_ = tanhfast(gg);
        float o_ = sigf(go);
        size_t cidx = (size_t)(b0 + row) * Hh + gcol;
        float cn = f_ * c[cidx] + i_ * g_;
        c[cidx] = cn;
        float hn = o_ * tanhfast(cn);
        h_next[cidx] = f2bf(hn);
    }
}

// ---------------- FC head: out = sigmoid(h @ W_fc^T + b_fc) ----------------
__global__ void fc_kernel(const ushort* __restrict__ h,      // bf16 [256][1024]
                          const float* __restrict__ Wfc,     // [8][1024]
                          const float* __restrict__ bfc,     // [8]
                          float* __restrict__ out) {         // [256][8]
    int b = blockIdx.x;
    int w = threadIdx.x >> 6;       // 0..7 -> output index
    int lane = threadIdx.x & 63;
    float s = 0.f;
    for (int k = lane; k < Hh; k += 64)
        s += bf2f(h[(size_t)b * Hh + k]) * Wfc[w * Hh + k];
    #pragma unroll
    for (int off = 32; off; off >>= 1) s += __shfl_down(s, off);
    if (lane == 0) out[b * NOUT + w] = sigf(s + bfc[w]);
}

extern "C" void kernel_launch(void* const* d_in, const int* in_sizes, int n_in,
                              void* d_out, int out_size, void* d_ws, size_t ws_size,
                              hipStream_t stream) {
    const float* x    = (const float*)d_in[0];
    const float* W_ih = (const float*)d_in[1];
    const float* W_hh = (const float*)d_in[2];
    const float* b_ih = (const float*)d_in[3];
    const float* b_hh = (const float*)d_in[4];
    const float* W_fc = (const float*)d_in[5];
    const float* b_fc = (const float*)d_in[6];
    float* out = (float*)d_out;

    char* ws = (char*)d_ws;
    // ws layout (bytes):
    //   [0, 1 MB)      h ping-pong, bf16 [2][256][1024]
    //   [1 MB, 2 MB)   c, fp32 [256][1024]
    //   [2 MB, 6 MB)   W_ih bf16 [4096][512]
    //   [6 MB, 14 MB)  W_hh bf16 [4096][1024]
    ushort* h_buf  = (ushort*)ws;
    float*  c_ws   = (float*)(ws + (1u << 20));
    ushort* wih_bf = (ushort*)(ws + (2u << 20));
    ushort* whh_bf = (ushort*)(ws + (6u << 20));

    init_kernel<<<256, 256, 0, stream>>>((uint4*)h_buf, (uint4*)c_ws);
    cvt_kernel<<<(G4 * Dd / 4) / 256, 256, 0, stream>>>((const float4*)W_ih, (ushort4*)wih_bf, G4 * Dd / 4);
    cvt_kernel<<<(G4 * Hh / 4) / 256, 256, 0, stream>>>((const float4*)W_hh, (ushort4*)whh_bf, G4 * Hh / 4);

    for (int t = 0; t < Tlen; ++t) {
        const ushort* hp = h_buf + (size_t)(t & 1) * Bsz * Hh;
        ushort*       hn = h_buf + (size_t)((t + 1) & 1) * Bsz * Hh;
        lstm_step<<<256, 256, 0, stream>>>(x, wih_bf, whh_bf, b_ih, b_hh, hp, hn, c_ws, t);
    }
    // after 512 steps (even), final h is in buffer 0
    fc_kernel<<<256, 512, 0, stream>>>(h_buf, W_fc, b_fc, out);
}